// Round 6
// baseline (138.378 us; speedup 1.0000x reference)
//
#include <hip/hip_runtime.h>
#include <stdint.h>

typedef unsigned int u32;
typedef unsigned long long u64;

#define HW      3136     // 56*56
#define PADW    58
#define PADHW   3364     // 58*58

// d_ws layout
#define WB_OFF   0        // 4608 u32  (18432 B)  packed weights
#define BF_OFF   18432    // 9*128 f32 (4608 B)   per-(class,o) base, alpha-folded
#define N2A_OFF  23040    // 128 f32   (512 B)    -2*alpha
#define AB_OFF   23552    // 32*3364 uint4        padded activation bits

// prep grid split
#define NB_W     128      // weight-synthesis blocks (one per o)
#define NB_A     392      // apack interior: 32 b * 4 g * 784 quads / 256
#define NB_R     29       // ring-zero: 32 b * 228 ring px -> 7296 uint4 / 256

// ---------------------------------------------------------------------------
// Prep kernel, 3 block classes (round-0 proven code, unchanged).
__global__ __launch_bounds__(256) void k_prep(
    const float* __restrict__ x, const float* __restrict__ Alpha,
    const float* __restrict__ M, const float* __restrict__ Z,
    const float* __restrict__ rv, char* __restrict__ ws)
{
  int t = threadIdx.x;
  if (blockIdx.x < NB_W) {
    // ---- weight synthesis for o = blockIdx.x ----
    u32*   wb  = (u32*)(ws + WB_OFF);
    float* Bf  = (float*)(ws + BF_OFF);
    float* n2a = (float*)(ws + N2A_OFF);
    __shared__ float sw[1152];
    __shared__ u32 sbits[36];
    __shared__ int spc[9];
    int o = blockIdx.x;
    float r0 = rv[0], r1 = rv[1], r2 = rv[2], r3 = rv[3], r4 = rv[4];
    const float4* M4 = (const float4*)M;
    const float4* Z4 = (const float4*)Z;
    float4* sw4 = (float4*)sw;

    for (int j = t; j < 288; j += 256) {
      float4 a = M4[o * 288 + j];
      float4 z;
      z = Z4[0 * 36864 + o * 288 + j];
      a.x = fmaf(r0, z.x, a.x); a.y = fmaf(r0, z.y, a.y);
      a.z = fmaf(r0, z.z, a.z); a.w = fmaf(r0, z.w, a.w);
      z = Z4[1 * 36864 + o * 288 + j];
      a.x = fmaf(r1, z.x, a.x); a.y = fmaf(r1, z.y, a.y);
      a.z = fmaf(r1, z.z, a.z); a.w = fmaf(r1, z.w, a.w);
      z = Z4[2 * 36864 + o * 288 + j];
      a.x = fmaf(r2, z.x, a.x); a.y = fmaf(r2, z.y, a.y);
      a.z = fmaf(r2, z.z, a.z); a.w = fmaf(r2, z.w, a.w);
      z = Z4[3 * 36864 + o * 288 + j];
      a.x = fmaf(r3, z.x, a.x); a.y = fmaf(r3, z.y, a.y);
      a.z = fmaf(r3, z.z, a.z); a.w = fmaf(r3, z.w, a.w);
      z = Z4[4 * 36864 + o * 288 + j];
      a.x = fmaf(r4, z.x, a.x); a.y = fmaf(r4, z.y, a.y);
      a.z = fmaf(r4, z.z, a.z); a.w = fmaf(r4, z.w, a.w);
      sw4[j] = a;
    }
    __syncthreads();

    if (t < 36) {                       // t = tap*4 + word
      int tap = t >> 2;
      int wd  = t & 3;
      u32 bits = 0;
#pragma unroll
      for (int c = 0; c < 32; ++c) {
        float v = sw[(wd * 32 + c) * 9 + tap];
        bits |= (v > 0.0f ? 1u : 0u) << c;
      }
      wb[(o * 9 + tap) * 4 + wd] = bits;
      sbits[t] = bits;
    }
    __syncthreads();
    if (t < 9)
      spc[t] = __popc(sbits[4 * t]) + __popc(sbits[4 * t + 1])
             + __popc(sbits[4 * t + 2]) + __popc(sbits[4 * t + 3]);
    __syncthreads();
    if (t < 9) {                        // t = edge class ht*3+wt
      int ht = t / 3, wt = t - ht * 3;
      int corr = 0;
#pragma unroll
      for (int tap = 0; tap < 9; ++tap) {
        int dh = tap / 3, dw = tap - dh * 3;
        int inv = ((ht == 0) & (dh == 0)) | ((ht == 2) & (dh == 2)) |
                  ((wt == 0) & (dw == 0)) | ((wt == 2) & (dw == 2));
        if (inv) corr += 128 - 2 * spc[tap];
      }
      Bf[t * 128 + o] = (float)(1152 - corr) * Alpha[o];
    }
    if (t == 0) n2a[o] = -2.0f * Alpha[o];
  } else if (blockIdx.x < NB_W + NB_A) {
    // ---- activation sign-pack, vectorized ----
    u32* abw = (u32*)(ws + AB_OFF);
    int idx = (blockIdx.x - NB_W) * 256 + t;  // (b*4+g)*784 + q
    int bg  = idx / 784;
    int q   = idx - bg * 784;                 // pixel quad 0..783
    int b   = bg >> 2;
    int g   = bg & 3;
    int h   = q / 14;                         // 4 | 56 -> no row wrap in quad
    int w0  = (q - h * 14) * 4;

    const float4* X4 = (const float4*)x
        + ((size_t)b * 128 + g * 32) * (HW / 4) + q;
    u32 m0 = 0, m1 = 0, m2 = 0, m3 = 0;
#pragma unroll
    for (int c = 0; c < 32; ++c) {
      float4 f = X4[(size_t)c * (HW / 4)];
      m0 |= (f.x > 0.0f ? 1u : 0u) << c;
      m1 |= (f.y > 0.0f ? 1u : 0u) << c;
      m2 |= (f.z > 0.0f ? 1u : 0u) << c;
      m3 |= (f.w > 0.0f ? 1u : 0u) << c;
    }
    size_t base = ((size_t)b * PADHW + (h + 1) * PADW + (w0 + 1)) * 4 + g;
    abw[base]      = m0;
    abw[base + 4]  = m1;
    abw[base + 8]  = m2;
    abw[base + 12] = m3;
  } else {
    // ---- ring zero ----
    uint4* ab4 = (uint4*)(ws + AB_OFF);
    int e = (blockIdx.x - NB_W - NB_A) * 256 + t;
    if (e >= 32 * 228) return;
    int b  = e / 228;
    int r  = e - b * 228;
    int pp;
    if      (r < 58)  pp = r;                       // top row
    else if (r < 116) pp = 57 * PADW + (r - 58);    // bottom row
    else {                                          // sides
      int s = r - 116;
      pp = (1 + (s >> 1)) * PADW + ((s & 1) ? 57 : 0);
    }
    ab4[(size_t)b * PADHW + pp] = make_uint4(0, 0, 0, 0);
  }
}

// ---------------------------------------------------------------------------
// Conv: thread = 1 pixel x 16 o's; weights in SGPRs via scalar loads.
//
// Round-5 diagnosis: with weights in LDS, the inner loop issues 144
// ds_read_b128/thread; VALUBusy 65% of 45 us = 29 us busy vs the 12.5 us
// xor/bcnt floor -> the LDS reads and their lgkmcnt waits ate the rest.
// Weights are BLOCK-UNIFORM (index = f(blockIdx.y, loop consts)), so read
// them straight from global through a uniform address: the backend's
// uniformity analysis emits s_load into SGPRs (both pointers __restrict__
// -> no alias), served by the scalar cache, zero VALU issue slots, no
// vector waits. Inner loop becomes pure v_xor(sgpr) + v_bcnt.
// #pragma unroll 2 bounds live weight SGPRs to 72/chunk (< ~102 budget).
// n2a[o0+oi] is also uniform -> scalar load. Only Bf stays in LDS (cl is
// per-thread divergent; 16 epilogue reads).
// A-tile = 3x3 uint4 = 36 VGPR (round-5 proven, no spill, occupancy 47%).
__global__ __launch_bounds__(256) void k_conv(
    const char* __restrict__ ws, float* __restrict__ out)
{
  const uint4* ab   = (const uint4*)(ws + AB_OFF);
  const u32*   wbw  = (const u32*)(ws + WB_OFF);
  const float* BfG  = (const float*)(ws + BF_OFF);
  const float* n2aG = (const float*)(ws + N2A_OFF);

  __shared__ float sBf[9][16];     // class x o  (only divergent-read table)
  int t  = threadIdx.x;            // 0..255
  int o0 = blockIdx.y * 16;
  if (t < 144)
    (&sBf[0][0])[t] = BfG[(t >> 4) * 128 + o0 + (t & 15)];
  __syncthreads();

  int gp = blockIdx.x * 256 + t;        // global pixel 0..100351
  int b  = gp / HW;
  int p  = gp - b * HW;
  int h  = p / 56;
  int w  = p - h * 56;

  // taps: padded rows h..h+2, cols w..w+2 (center at padded (h+1,w+1))
  const uint4* ap = ab + (size_t)b * PADHW + (size_t)h * PADW + w;
  u32 A[9][4];
#pragma unroll
  for (int rr = 0; rr < 3; ++rr)
#pragma unroll
    for (int cc = 0; cc < 3; ++cc) {
      uint4 v = ap[(size_t)rr * PADW + cc];
      A[rr * 3 + cc][0] = v.x; A[rr * 3 + cc][1] = v.y;
      A[rr * 3 + cc][2] = v.z; A[rr * 3 + cc][3] = v.w;
    }

  int cl = ((h == 0) ? 0 : (h == 55 ? 6 : 3))
         + ((w == 0) ? 0 : (w == 55 ? 2 : 1));

  float* outp = out + ((size_t)b * 128 + o0) * HW + p;

#pragma unroll 2
  for (int oi = 0; oi < 16; ++oi) {
    const u32* wp = wbw + (size_t)(o0 + oi) * 36;   // uniform -> s_load
    int s = 0;
#pragma unroll
    for (int tap = 0; tap < 9; ++tap) {
      s += __popc(A[tap][0] ^ wp[tap * 4 + 0]);
      s += __popc(A[tap][1] ^ wp[tap * 4 + 1]);
      s += __popc(A[tap][2] ^ wp[tap * 4 + 2]);
      s += __popc(A[tap][3] ^ wp[tap * 4 + 3]);
    }
    float ov = fmaf((float)s, n2aG[o0 + oi], sBf[cl][oi]);
    __builtin_nontemporal_store(ov, outp + (size_t)oi * HW);
  }
}

// ---------------------------------------------------------------------------
extern "C" void kernel_launch(void* const* d_in, const int* in_sizes, int n_in,
                              void* d_out, int out_size, void* d_ws, size_t ws_size,
                              hipStream_t stream)
{
  const float* x     = (const float*)d_in[0];
  const float* Alpha = (const float*)d_in[1];
  const float* M     = (const float*)d_in[2];
  const float* Z     = (const float*)d_in[3];
  const float* rv    = (const float*)d_in[4];
  float* out         = (float*)d_out;
  char*  ws          = (char*)d_ws;

  k_prep<<<NB_W + NB_A + NB_R, 256, 0, stream>>>(x, Alpha, M, Z, rv, ws);
  k_conv<<<dim3(392, 8), 256, 0, stream>>>(ws, out);
}

// Round 7
// 137.452 us; speedup vs baseline: 1.0067x; 1.0067x over previous
//
#include <hip/hip_runtime.h>
#include <stdint.h>

typedef unsigned int u32;
typedef unsigned long long u64;

#define HW      3136     // 56*56
#define PADW    58
#define PADHW   3364     // 58*58

// d_ws layout
#define WB_OFF   0        // 4608 u32  (18432 B)  packed weights
#define BF_OFF   18432    // 9*128 f32 (4608 B)   per-(class,o) base, alpha-folded
#define N2A_OFF  23040    // 128 f32   (512 B)    -2*alpha
#define AB_OFF   23552    // 32*3364 uint4        padded activation bits

// prep grid split
#define NB_W     128      // weight-synthesis blocks (one per o)
#define NB_A     392      // apack interior: 32 b * 4 g * 784 quads / 256
#define NB_R     29       // ring-zero: 32 b * 228 ring px -> 7296 uint4 / 256

// ---------------------------------------------------------------------------
// Prep kernel, 3 block classes (round-0 proven code, unchanged).
__global__ __launch_bounds__(256) void k_prep(
    const float* __restrict__ x, const float* __restrict__ Alpha,
    const float* __restrict__ M, const float* __restrict__ Z,
    const float* __restrict__ rv, char* __restrict__ ws)
{
  int t = threadIdx.x;
  if (blockIdx.x < NB_W) {
    // ---- weight synthesis for o = blockIdx.x ----
    u32*   wb  = (u32*)(ws + WB_OFF);
    float* Bf  = (float*)(ws + BF_OFF);
    float* n2a = (float*)(ws + N2A_OFF);
    __shared__ float sw[1152];
    __shared__ u32 sbits[36];
    __shared__ int spc[9];
    int o = blockIdx.x;
    float r0 = rv[0], r1 = rv[1], r2 = rv[2], r3 = rv[3], r4 = rv[4];
    const float4* M4 = (const float4*)M;
    const float4* Z4 = (const float4*)Z;
    float4* sw4 = (float4*)sw;

    for (int j = t; j < 288; j += 256) {
      float4 a = M4[o * 288 + j];
      float4 z;
      z = Z4[0 * 36864 + o * 288 + j];
      a.x = fmaf(r0, z.x, a.x); a.y = fmaf(r0, z.y, a.y);
      a.z = fmaf(r0, z.z, a.z); a.w = fmaf(r0, z.w, a.w);
      z = Z4[1 * 36864 + o * 288 + j];
      a.x = fmaf(r1, z.x, a.x); a.y = fmaf(r1, z.y, a.y);
      a.z = fmaf(r1, z.z, a.z); a.w = fmaf(r1, z.w, a.w);
      z = Z4[2 * 36864 + o * 288 + j];
      a.x = fmaf(r2, z.x, a.x); a.y = fmaf(r2, z.y, a.y);
      a.z = fmaf(r2, z.z, a.z); a.w = fmaf(r2, z.w, a.w);
      z = Z4[3 * 36864 + o * 288 + j];
      a.x = fmaf(r3, z.x, a.x); a.y = fmaf(r3, z.y, a.y);
      a.z = fmaf(r3, z.z, a.z); a.w = fmaf(r3, z.w, a.w);
      z = Z4[4 * 36864 + o * 288 + j];
      a.x = fmaf(r4, z.x, a.x); a.y = fmaf(r4, z.y, a.y);
      a.z = fmaf(r4, z.z, a.z); a.w = fmaf(r4, z.w, a.w);
      sw4[j] = a;
    }
    __syncthreads();

    if (t < 36) {                       // t = tap*4 + word
      int tap = t >> 2;
      int wd  = t & 3;
      u32 bits = 0;
#pragma unroll
      for (int c = 0; c < 32; ++c) {
        float v = sw[(wd * 32 + c) * 9 + tap];
        bits |= (v > 0.0f ? 1u : 0u) << c;
      }
      wb[(o * 9 + tap) * 4 + wd] = bits;
      sbits[t] = bits;
    }
    __syncthreads();
    if (t < 9)
      spc[t] = __popc(sbits[4 * t]) + __popc(sbits[4 * t + 1])
             + __popc(sbits[4 * t + 2]) + __popc(sbits[4 * t + 3]);
    __syncthreads();
    if (t < 9) {                        // t = edge class ht*3+wt
      int ht = t / 3, wt = t - ht * 3;
      int corr = 0;
#pragma unroll
      for (int tap = 0; tap < 9; ++tap) {
        int dh = tap / 3, dw = tap - dh * 3;
        int inv = ((ht == 0) & (dh == 0)) | ((ht == 2) & (dh == 2)) |
                  ((wt == 0) & (dw == 0)) | ((wt == 2) & (dw == 2));
        if (inv) corr += 128 - 2 * spc[tap];
      }
      Bf[t * 128 + o] = (float)(1152 - corr) * Alpha[o];
    }
    if (t == 0) n2a[o] = -2.0f * Alpha[o];
  } else if (blockIdx.x < NB_W + NB_A) {
    // ---- activation sign-pack, vectorized ----
    u32* abw = (u32*)(ws + AB_OFF);
    int idx = (blockIdx.x - NB_W) * 256 + t;  // (b*4+g)*784 + q
    int bg  = idx / 784;
    int q   = idx - bg * 784;                 // pixel quad 0..783
    int b   = bg >> 2;
    int g   = bg & 3;
    int h   = q / 14;                         // 4 | 56 -> no row wrap in quad
    int w0  = (q - h * 14) * 4;

    const float4* X4 = (const float4*)x
        + ((size_t)b * 128 + g * 32) * (HW / 4) + q;
    u32 m0 = 0, m1 = 0, m2 = 0, m3 = 0;
#pragma unroll
    for (int c = 0; c < 32; ++c) {
      float4 f = X4[(size_t)c * (HW / 4)];
      m0 |= (f.x > 0.0f ? 1u : 0u) << c;
      m1 |= (f.y > 0.0f ? 1u : 0u) << c;
      m2 |= (f.z > 0.0f ? 1u : 0u) << c;
      m3 |= (f.w > 0.0f ? 1u : 0u) << c;
    }
    size_t base = ((size_t)b * PADHW + (h + 1) * PADW + (w0 + 1)) * 4 + g;
    abw[base]      = m0;
    abw[base + 4]  = m1;
    abw[base + 8]  = m2;
    abw[base + 12] = m3;
  } else {
    // ---- ring zero ----
    uint4* ab4 = (uint4*)(ws + AB_OFF);
    int e = (blockIdx.x - NB_W - NB_A) * 256 + t;
    if (e >= 32 * 228) return;
    int b  = e / 228;
    int r  = e - b * 228;
    int pp;
    if      (r < 58)  pp = r;                       // top row
    else if (r < 116) pp = 57 * PADW + (r - 58);    // bottom row
    else {                                          // sides
      int s = r - 116;
      pp = (1 + (s >> 1)) * PADW + ((s & 1) ? 57 : 0);
    }
    ab4[(size_t)b * PADHW + pp] = make_uint4(0, 0, 0, 0);
  }
}

// ---------------------------------------------------------------------------
// Conv: thread = 1 pixel x 16 o's; weights in SGPRs (round-6 proven:
// SGPR 80, VGPR 32, zero bank conflicts, WRITE = exactly output size).
//
// Round-6 diagnosis: occupancy 50% -- grid (392,8) = 12.25 blocks/CU x 4
// waves = 16/32 waves/CU, while VGPR=32 permits 32.  With 4 waves/SIMD
// the 36-deep dependent popc chain (4-cyc latency each) + per-oi-pair
// scalar-load lgkmcnt waits can't be hidden -> VALUBusy 65%, 41.7 us.
// Fix 1: 128-thread blocks, grid (784,8) = 24.5 blocks/CU x 2 waves ->
//        resident 16 blocks/CU = 32 waves = 100% occupancy cap.
// Fix 2: dual accumulators (taps 0-3 -> sa, 4-8 -> sb) halve the
//        dependent chain so each wave issues ~2x as often.
// Issue floor ~13 us chip-wide; expect ~22-28 us.
__global__ __launch_bounds__(128) void k_conv(
    const char* __restrict__ ws, float* __restrict__ out)
{
  const uint4* ab   = (const uint4*)(ws + AB_OFF);
  const u32*   wbw  = (const u32*)(ws + WB_OFF);
  const float* BfG  = (const float*)(ws + BF_OFF);
  const float* n2aG = (const float*)(ws + N2A_OFF);

  __shared__ float sBf[9][16];     // class x o  (only divergent-read table)
  int t  = threadIdx.x;            // 0..127
  int o0 = blockIdx.y * 16;
  for (int j = t; j < 144; j += 128)
    (&sBf[0][0])[j] = BfG[(j >> 4) * 128 + o0 + (j & 15)];
  __syncthreads();

  int gp = blockIdx.x * 128 + t;        // global pixel 0..100351
  int b  = gp / HW;
  int p  = gp - b * HW;
  int h  = p / 56;
  int w  = p - h * 56;

  // taps: padded rows h..h+2, cols w..w+2 (center at padded (h+1,w+1))
  const uint4* ap = ab + (size_t)b * PADHW + (size_t)h * PADW + w;
  u32 A[9][4];
#pragma unroll
  for (int rr = 0; rr < 3; ++rr)
#pragma unroll
    for (int cc = 0; cc < 3; ++cc) {
      uint4 v = ap[(size_t)rr * PADW + cc];
      A[rr * 3 + cc][0] = v.x; A[rr * 3 + cc][1] = v.y;
      A[rr * 3 + cc][2] = v.z; A[rr * 3 + cc][3] = v.w;
    }

  int cl = ((h == 0) ? 0 : (h == 55 ? 6 : 3))
         + ((w == 0) ? 0 : (w == 55 ? 2 : 1));

  float* outp = out + ((size_t)b * 128 + o0) * HW + p;

#pragma unroll 2
  for (int oi = 0; oi < 16; ++oi) {
    const u32* wp = wbw + (size_t)(o0 + oi) * 36;   // uniform -> s_load
    int sa = 0, sb = 0;
#pragma unroll
    for (int tap = 0; tap < 4; ++tap) {
      sa += __popc(A[tap][0] ^ wp[tap * 4 + 0]);
      sa += __popc(A[tap][1] ^ wp[tap * 4 + 1]);
      sa += __popc(A[tap][2] ^ wp[tap * 4 + 2]);
      sa += __popc(A[tap][3] ^ wp[tap * 4 + 3]);
    }
#pragma unroll
    for (int tap = 4; tap < 9; ++tap) {
      sb += __popc(A[tap][0] ^ wp[tap * 4 + 0]);
      sb += __popc(A[tap][1] ^ wp[tap * 4 + 1]);
      sb += __popc(A[tap][2] ^ wp[tap * 4 + 2]);
      sb += __popc(A[tap][3] ^ wp[tap * 4 + 3]);
    }
    float ov = fmaf((float)(sa + sb), n2aG[o0 + oi], sBf[cl][oi]);
    __builtin_nontemporal_store(ov, outp + (size_t)oi * HW);
  }
}

// ---------------------------------------------------------------------------
extern "C" void kernel_launch(void* const* d_in, const int* in_sizes, int n_in,
                              void* d_out, int out_size, void* d_ws, size_t ws_size,
                              hipStream_t stream)
{
  const float* x     = (const float*)d_in[0];
  const float* Alpha = (const float*)d_in[1];
  const float* M     = (const float*)d_in[2];
  const float* Z     = (const float*)d_in[3];
  const float* rv    = (const float*)d_in[4];
  float* out         = (float*)d_out;
  char*  ws          = (char*)d_ws;

  k_prep<<<NB_W + NB_A + NB_R, 256, 0, stream>>>(x, Alpha, M, Z, rv, ws);
  k_conv<<<dim3(784, 8), 128, 0, stream>>>(ws, out);
}